// Round 7
// baseline (4721.198 us; speedup 1.0000x reference)
//
#include <hip/hip_runtime.h>

// Problem constants
#define B_  4096
#define T_  64
#define D_  256
#define E_  128
#define H_  256

typedef __attribute__((ext_vector_type(8))) short short8;
typedef __attribute__((ext_vector_type(4))) float f32x4;
typedef __attribute__((ext_vector_type(16))) float f32x16;

__device__ inline unsigned short f2bf(float f){
  unsigned u = __float_as_uint(f);
  u += 0x7FFFu + ((u >> 16) & 1u);   // RNE
  return (unsigned short)(u >> 16);
}
__device__ inline float bf2f(unsigned short v){
  return __uint_as_float(((unsigned)v) << 16);
}
__device__ inline float sigm_(float x){ return __fdividef(1.f, 1.f + __expf(-x)); }
__device__ inline float tanh_(float x){
  float e = __expf(2.f * fminf(fmaxf(x, -15.f), 15.f));
  return __fdividef(e - 1.f, e + 1.f);
}
__device__ inline short8 ntload8(const unsigned short* p){
  return __builtin_nontemporal_load((const short8*)p);
}
__device__ inline f32x4 ntload4f(const float* p){
  return __builtin_nontemporal_load((const f32x4*)p);
}

// ---------------------------------------------------------------------------
// init: pack weights as 32x32x16 MFMA A-fragments, per slice.
// Wf elem idx = ((s*4 + nf)*24 + ks)*512 + l*8 + e
//   A-row r = l&31 -> q = r&3, hl = r>>2 ; h = s*32 + nf*8 + hl
//   k = ks*16 + (l>>5)*8 + e ;  g = q*256 + h
//   val = k<128 ? W_ih[g][k] : W_hh[g][k-128]
// Also: biasc[h*4+q]; zero hglob buf0 (2 MB); zero cnt[32].
// grid 1536 x 256 (= 393216 weight elems).
// ---------------------------------------------------------------------------
__global__ __launch_bounds__(256) void init_kernel(
    const float* __restrict__ W_ih, const float* __restrict__ b_ih,
    const float* __restrict__ W_hh, const float* __restrict__ b_hh,
    unsigned short* __restrict__ Wf, float* __restrict__ biasc,
    unsigned short* __restrict__ hg0, int* __restrict__ cnt){
  const int idx  = blockIdx.x*256 + threadIdx.x;
  const int e    = idx & 7;
  const int l    = (idx >> 3) & 63;
  const int fk   = idx >> 9;          // 0..767 = (s*4+nf)*24 + ks
  const int ks   = fk % 24;
  const int nfs  = fk / 24;           // s*4+nf
  const int nf   = nfs & 3;
  const int s    = nfs >> 2;
  const int r    = l & 31;
  const int q    = r & 3;
  const int hl   = r >> 2;
  const int h    = s*32 + nf*8 + hl;
  const int k    = ks*16 + (l >> 5)*8 + e;
  const int g    = q*H_ + h;
  float v = (k < E_) ? W_ih[g*E_ + k] : W_hh[g*H_ + (k - E_)];
  Wf[idx] = f2bf(v);
  if (idx < 4*H_){
    int hh = idx >> 2, qq = idx & 3, gg = qq*H_ + hh;
    biasc[idx] = b_ih[gg] + b_hh[gg];
  }
  if (idx < 262144) ((unsigned long long*)hg0)[idx] = 0ull;  // 2 MB zeros
  if (idx < 32) cnt[idx] = 0;
}

// ---------------------------------------------------------------------------
// encT[t][b][e] = bf16(tanh(x @ W_enc^T + b_enc)), MFMA 16x16x32 bf16.
// ---------------------------------------------------------------------------
__global__ __launch_bounds__(256) void enc_kernel(
    const float* __restrict__ x, const float* __restrict__ W_enc,
    const float* __restrict__ b_enc, unsigned short* __restrict__ encT){
  __shared__ unsigned short As[128*64];
  __shared__ unsigned short Bs[128*64];
  __shared__ float bes[128];
  const int tid = threadIdx.x;
  const int lane = tid & 63, w = tid >> 6;
  const int l15 = lane & 15, lq = lane >> 4;
  const int m0 = blockIdx.x * 128;
  if (tid < 128) bes[tid] = b_enc[tid];

  f32x4 acc[16];
  #pragma unroll
  for (int i=0;i<16;i++) acc[i] = (f32x4)0.f;

  for (int kc = 0; kc < 4; ++kc){
    const int kb = kc*64;
    __syncthreads();
    #pragma unroll
    for (int i=0;i<4;i++){
      int u = i*256 + tid; int r = u>>3, sx = u&7;
      const float* sp = x + (size_t)(m0+r)*D_ + kb + sx*8;
      f32x4 v0 = ntload4f(sp);
      f32x4 v1 = ntload4f(sp+4);
      short8 pk;
      pk[0]=(short)f2bf(v0[0]); pk[1]=(short)f2bf(v0[1]); pk[2]=(short)f2bf(v0[2]); pk[3]=(short)f2bf(v0[3]);
      pk[4]=(short)f2bf(v1[0]); pk[5]=(short)f2bf(v1[1]); pk[6]=(short)f2bf(v1[2]); pk[7]=(short)f2bf(v1[3]);
      int off = (r*128 + sx*16) ^ ((r&7)<<4);
      *(short8*)((char*)As + off) = pk;
    }
    #pragma unroll
    for (int i=0;i<4;i++){
      int u = i*256 + tid; int r = u>>3, sx = u&7;
      const float* sp = W_enc + (size_t)r*D_ + kb + sx*8;
      f32x4 v0 = *(const f32x4*)sp;
      f32x4 v1 = *(const f32x4*)(sp+4);
      short8 pk;
      pk[0]=(short)f2bf(v0[0]); pk[1]=(short)f2bf(v0[1]); pk[2]=(short)f2bf(v0[2]); pk[3]=(short)f2bf(v0[3]);
      pk[4]=(short)f2bf(v1[0]); pk[5]=(short)f2bf(v1[1]); pk[6]=(short)f2bf(v1[2]); pk[7]=(short)f2bf(v1[3]);
      int off = (r*128 + sx*16) ^ ((r&7)<<4);
      *(short8*)((char*)Bs + off) = pk;
    }
    __syncthreads();
    #pragma unroll
    for (int kk=0;kk<2;kk++){
      short8 af[2];
      #pragma unroll
      for (int mi=0;mi<2;mi++){
        int r = 32*w + mi*16 + l15;
        int off = (r*128 + kk*64 + lq*16) ^ ((r&7)<<4);
        af[mi] = *(const short8*)((const char*)As + off);
      }
      #pragma unroll
      for (int nf=0;nf<8;nf++){
        int r = nf*16 + l15;
        int off = (r*128 + kk*64 + lq*16) ^ ((r&7)<<4);
        short8 bfr = *(const short8*)((const char*)Bs + off);
        #pragma unroll
        for (int mi=0;mi<2;mi++)
          acc[mi*8+nf] = __builtin_amdgcn_mfma_f32_16x16x32_bf16(af[mi], bfr, acc[mi*8+nf], 0,0,0);
      }
    }
  }
  #pragma unroll
  for (int mi=0;mi<2;mi++){
    #pragma unroll
    for (int nf=0;nf<8;nf++){
      int col = nf*16 + l15;
      float be = bes[col];
      #pragma unroll
      for (int j=0;j<4;j++){
        int bt = m0 + 32*w + mi*16 + lq*4 + j;
        int b = bt >> 6, tt = bt & 63;
        encT[((size_t)tt*B_ + b)*E_ + col] = f2bf(tanh_(acc[mi*8+nf][j] + be));
      }
    }
  }
}

// ---------------------------------------------------------------------------
// Gate-split cooperative LSTM recurrence.
// 256 blocks x 512 threads. block = (grp = id&31 -> 128 batch rows,
// s = id>>5 -> h-slice [s*32,s*32+32) x 4 gates). Weights (96 KB) in LDS,
// loaded ONCE. h (bf16, dbuf) exchanged via global + per-group barrier.
// MFMA 32x32x16: A = weights (rows = 32 gates, r=hl*4+q), B = activations
// (cols = 32 batch rows). Lane's 16 acc regs = 4 cells x 4 gates.
// ---------------------------------------------------------------------------
__global__ __launch_bounds__(512, 2) void rec_kernel(
    const unsigned short* __restrict__ encT,
    const unsigned short* __restrict__ Wf,
    const float* __restrict__ biasc,
    const float* __restrict__ x,
    unsigned short* __restrict__ hg,     // 2 buffers, stride 1048576 elems
    int* __restrict__ cnt,
    unsigned short* __restrict__ psq,    // [63][8][4096] bf16
    float* __restrict__ out_hn,
    float* __restrict__ out_ldim,
    float* __restrict__ out_ldt){
  extern __shared__ char wlds[];         // 96 KB weight slice
  __shared__ float psq_lds[128];
  const int tid = threadIdx.x, lane = tid & 63, w = tid >> 6;
  const int l31 = lane & 31, l5 = lane >> 5;
  const int s   = blockIdx.x >> 5;
  const int grp = blockIdx.x & 31;
  const int b0g = grp * 128;
  const int gfr = w & 3, p = w >> 2;
  const int bgA = 2*p, bgB = 2*p + 1;

  // weights -> LDS (linear, coalesced)
  {
    const short8* src = (const short8*)(Wf + (size_t)s*49152);
    short8* dst = (short8*)wlds;
    for (int i = tid; i < 6144; i += 512) dst[i] = src[i];
  }
  if (tid < 128) psq_lds[tid] = 0.f;

  // per-reg biases (same for both batch groups)
  float biasr[16];
  #pragma unroll
  for (int r=0;r<16;r++){
    int q = r & 3, r2 = r >> 2;
    int h = s*32 + gfr*8 + l5 + 2*r2;
    biasr[r] = biasc[h*4 + q];
  }

  const int rowA = b0g + bgA*32 + l31;
  const int rowB = b0g + bgB*32 + l31;
  const int hcol0 = s*32 + gfr*8 + l5;        // + 2*r2
  const unsigned short* encA = encT + (size_t)rowA*E_ + l5*8;
  const unsigned short* encB = encT + (size_t)rowB*E_ + l5*8;
  const char* ab = wlds + ((gfr*24) << 10) + lane*16;

  float c[8], ldim[8];
  #pragma unroll
  for (int i=0;i<8;i++){ c[i] = 0.f; ldim[i] = 0.f; }

  __syncthreads();   // LDS weights + psq_lds ready

  for (int t=0; t<T_; ++t){
    // 1. prefetch enc B-frags + x (constants; overlap with spin)
    short8 be0[8], be1[8];
    #pragma unroll
    for (int ks=0;ks<8;ks++){
      be0[ks] = ntload8(encA + (size_t)t*B_*E_ + ks*16);
      be1[ks] = ntload8(encB + (size_t)t*B_*E_ + ks*16);
    }
    float xv0[4], xv1[4];
    if (t < T_-1){
      #pragma unroll
      for (int r2=0;r2<4;r2++){
        xv0[r2] = x[((size_t)rowA*T_ + t+1)*D_ + hcol0 + 2*r2];
        xv1[r2] = x[((size_t)rowB*T_ + t+1)*D_ + hcol0 + 2*r2];
      }
    }
    // 2. group barrier: arrive (release) + spin (acquire)
    if (tid == 0){
      __builtin_amdgcn_fence(__ATOMIC_RELEASE, "agent");
      __hip_atomic_fetch_add(cnt + grp, 1, __ATOMIC_RELEASE, __HIP_MEMORY_SCOPE_AGENT);
      const int target = 8*(t+1);
      int guard = 0;
      while (__hip_atomic_load(cnt + grp, __ATOMIC_ACQUIRE, __HIP_MEMORY_SCOPE_AGENT) < target){
        if (++guard > (1<<22)) break;   // bail -> visible wrong result, not a hang
        __builtin_amdgcn_s_sleep(2);
      }
    }
    __syncthreads();
    __builtin_amdgcn_fence(__ATOMIC_ACQUIRE, "agent");

    // 3. MFMA: K = 128 enc + 256 h
    const unsigned short* hbufR = hg + ((t & 1) ? 1048576 : 0);
    const unsigned short* hA = hbufR + (size_t)rowA*H_ + l5*8;
    const unsigned short* hB = hbufR + (size_t)rowB*H_ + l5*8;
    f32x16 a0 = (f32x16)0.f, a1 = (f32x16)0.f;
    #pragma unroll
    for (int ks=0;ks<8;ks++){
      short8 A = *(const short8*)(ab + (ks<<10));
      a0 = __builtin_amdgcn_mfma_f32_32x32x16_bf16(A, be0[ks], a0, 0,0,0);
      a1 = __builtin_amdgcn_mfma_f32_32x32x16_bf16(A, be1[ks], a1, 0,0,0);
    }
    #pragma unroll
    for (int ks=0;ks<16;ks++){
      short8 A  = *(const short8*)(ab + ((8+ks)<<10));
      short8 B0 = *(const short8*)(hA + ks*16);
      short8 B1 = *(const short8*)(hB + ks*16);
      a0 = __builtin_amdgcn_mfma_f32_32x32x16_bf16(A, B0, a0, 0,0,0);
      a1 = __builtin_amdgcn_mfma_f32_32x32x16_bf16(A, B1, a1, 0,0,0);
    }

    // 4. pointwise: lane owns 4 cells x 2 rows
    unsigned short* hbufW = hg + (((t+1) & 1) ? 1048576 : 0);
    float v0 = 0.f, v1 = 0.f;
    #pragma unroll
    for (int r2=0;r2<4;r2++){
      const int h = hcol0 + 2*r2;
      {
        float gi = sigm_(a0[r2*4+0] + biasr[r2*4+0]);
        float gf = sigm_(a0[r2*4+1] + biasr[r2*4+1]);
        float gg = tanh_(a0[r2*4+2] + biasr[r2*4+2]);
        float go = sigm_(a0[r2*4+3] + biasr[r2*4+3]);
        float cn = gf*c[r2] + gi*gg;
        c[r2] = cn;
        float hn = go * tanh_(cn);
        hbufW[(size_t)rowA*H_ + h] = f2bf(hn);
        if (t < T_-1){
          float d = fabsf(hn - xv0[r2]);
          __builtin_nontemporal_store(d, out_ldt + ((size_t)rowA*T_ + t)*H_ + h);
          ldim[r2] += d;  v0 += d*d;
        } else {
          __builtin_nontemporal_store(0.f, out_ldt + ((size_t)rowA*T_ + t)*H_ + h);
          __builtin_nontemporal_store(hn, out_hn + (size_t)rowA*H_ + h);
        }
      }
      {
        float gi = sigm_(a1[r2*4+0] + biasr[r2*4+0]);
        float gf = sigm_(a1[r2*4+1] + biasr[r2*4+1]);
        float gg = tanh_(a1[r2*4+2] + biasr[r2*4+2]);
        float go = sigm_(a1[r2*4+3] + biasr[r2*4+3]);
        float cn = gf*c[4+r2] + gi*gg;
        c[4+r2] = cn;
        float hn = go * tanh_(cn);
        hbufW[(size_t)rowB*H_ + h] = f2bf(hn);
        if (t < T_-1){
          float d = fabsf(hn - xv1[r2]);
          __builtin_nontemporal_store(d, out_ldt + ((size_t)rowB*T_ + t)*H_ + h);
          ldim[4+r2] += d;  v1 += d*d;
        } else {
          __builtin_nontemporal_store(0.f, out_ldt + ((size_t)rowB*T_ + t)*H_ + h);
          __builtin_nontemporal_store(hn, out_hn + (size_t)rowB*H_ + h);
        }
      }
    }

    // 5. loss partials: reduce lane pairs (l ^ 32 share the batch row)
    if (t < T_-1){
      v0 += __shfl_xor(v0, 32);
      v1 += __shfl_xor(v1, 32);
      if (lane < 32){
        atomicAdd(psq_lds + bgA*32 + l31, v0);
        atomicAdd(psq_lds + bgB*32 + l31, v1);
      }
    }
    __syncthreads();   // drains all h stores too (pre-arrival requirement)
    if (t < T_-1 && tid < 128){
      float pv = psq_lds[tid];
      psq_lds[tid] = 0.f;
      psq[((size_t)t*8 + s)*4096 + b0g + tid] = f2bf(pv);
    }
  }

  // epilogue: loss_dim
  const float inv = 1.f/63.f;
  #pragma unroll
  for (int r2=0;r2<4;r2++){
    const int h = hcol0 + 2*r2;
    out_ldim[(size_t)rowA*H_ + h] = ldim[r2]   * inv;
    out_ldim[(size_t)rowB*H_ + h] = ldim[4+r2] * inv;
  }
}

// ---------------------------------------------------------------------------
// final: loss[b] = (1/63) sum_t sqrt(sum_s psq[t][s][b]). grid 16 x 256.
// ---------------------------------------------------------------------------
__global__ __launch_bounds__(256) void final_kernel(
    const unsigned short* __restrict__ psq, float* __restrict__ out_loss){
  const int w = threadIdx.x >> 6, lane = threadIdx.x & 63;
  const int b = (blockIdx.x*4 + w)*64 + lane;
  float lacc = 0.f;
  for (int t=0;t<T_-1;++t){
    float sum = 0.f;
    #pragma unroll
    for (int s=0;s<8;s++) sum += bf2f(psq[((size_t)t*8 + s)*4096 + b]);
    lacc += sqrtf(sum);
  }
  out_loss[b] = lacc * (1.f/63.f);
}

// ---------------------------------------------------------------------------
extern "C" void kernel_launch(void* const* d_in, const int* in_sizes, int n_in,
                              void* d_out, int out_size, void* d_ws, size_t ws_size,
                              hipStream_t stream){
  const float* x     = (const float*)d_in[0];
  const float* W_enc = (const float*)d_in[1];
  const float* b_enc = (const float*)d_in[2];
  const float* W_ih  = (const float*)d_in[3];
  const float* b_ih  = (const float*)d_in[4];
  const float* W_hh  = (const float*)d_in[5];
  const float* b_hh  = (const float*)d_in[6];

  // workspace: encT 64MB | Wf 768KB | biasc 4KB | hg 4MB | cnt 128B | psq 4MB
  char* ws = (char*)d_ws;
  unsigned short* encT  = (unsigned short*)(ws);                 // 67,108,864
  unsigned short* Wf    = (unsigned short*)(ws + 67108864);      //    786,432
  float*          biasc = (float*)         (ws + 67895296);      //      4,096
  unsigned short* hg    = (unsigned short*)(ws + 67899392);      //  4,194,304
  int*            cnt   = (int*)           (ws + 72093696);      //        128
  unsigned short* psq   = (unsigned short*)(ws + 72093824);      //  4,128,768
  // total 76,222,592 B

  float* out_hn   = (float*)d_out;
  float* out_loss = out_hn  + (size_t)B_*H_;
  float* out_ldim = out_loss + B_;
  float* out_ldt  = out_ldim + (size_t)B_*H_;

  (void)hipFuncSetAttribute((const void*)rec_kernel,
      hipFuncAttributeMaxDynamicSharedMemorySize, 98304);

  init_kernel<<<1536, 256, 0, stream>>>(W_ih, b_ih, W_hh, b_hh, Wf, biasc, hg, cnt);
  enc_kernel<<<2048, 256, 0, stream>>>(x, W_enc, b_enc, encT);

  {
    const unsigned short* encT_c = encT;
    const unsigned short* Wf_c   = Wf;
    const float* biasc_c = biasc;
    const float* x_c = x;
    unsigned short* hg_p = hg;
    int* cnt_p = cnt;
    unsigned short* psq_p = psq;
    float* hn_p = out_hn;
    float* ldim_p = out_ldim;
    float* ldt_p = out_ldt;
    void* args[] = { &encT_c, &Wf_c, &biasc_c, &x_c, &hg_p, &cnt_p, &psq_p,
                     &hn_p, &ldim_p, &ldt_p };
    (void)hipLaunchCooperativeKernel((void*)rec_kernel, dim3(256), dim3(512),
                                     args, 98304, stream);
  }

  final_kernel<<<16, 256, 0, stream>>>(psq, out_loss);
}

// Round 8
// 1889.712 us; speedup vs baseline: 2.4984x; 2.4984x over previous
//
#include <hip/hip_runtime.h>

// Problem constants
#define B_  4096
#define T_  64
#define D_  256
#define E_  128
#define H_  256

typedef __attribute__((ext_vector_type(8))) short short8;
typedef __attribute__((ext_vector_type(4))) float f32x4;
typedef __attribute__((ext_vector_type(2))) unsigned int u32x2;

__device__ inline unsigned short f2bf(float f){
  unsigned u = __float_as_uint(f);
  u += 0x7FFFu + ((u >> 16) & 1u);   // RNE
  return (unsigned short)(u >> 16);
}
__device__ inline float sigm_(float x){ return __fdividef(1.f, 1.f + __expf(-x)); }
__device__ inline float tanh_(float x){
  float e = __expf(2.f * fminf(fmaxf(x, -15.f), 15.f));
  return __fdividef(e - 1.f, e + 1.f);
}
__device__ inline short8 ntload8(const unsigned short* p){
  return __builtin_nontemporal_load((const short8*)p);
}
__device__ inline f32x4 ntload4f(const float* p){
  return __builtin_nontemporal_load((const f32x4*)p);
}

// ---------------------------------------------------------------------------
// init: pack weights into per-wave MFMA fragment order (16 wave-slices).
// Wf idx: frag = (w*12 + kk)*4 + q ; elem = frag*512 + lane*8 + e
//   = W'[(w*16 + (lane&15))*4 + q][kk*32 + (lane>>4)*8 + e]
//   W'[h*4+q][k] = k<128 ? W_ih[q*256+h][k] : W_hh[q*256+h][k-128]
// biasc[h*4+q] = b_ih[q*256+h] + b_hh[q*256+h].  grid 1536 x 256.
// ---------------------------------------------------------------------------
__global__ __launch_bounds__(256) void init_kernel(
    const float* __restrict__ W_ih, const float* __restrict__ b_ih,
    const float* __restrict__ W_hh, const float* __restrict__ b_hh,
    unsigned short* __restrict__ Wf, float* __restrict__ biasc){
  const int idx  = blockIdx.x*256 + threadIdx.x;
  const int e    = idx & 7;
  const int lane = (idx >> 3) & 63;
  const int frag = idx >> 9;          // 0..767
  const int q    = frag & 3;
  const int fk   = frag >> 2;         // 0..191
  const int kk   = fk % 12;
  const int w    = fk / 12;
  const int h    = w*16 + (lane & 15);
  const int k    = kk*32 + (lane >> 4)*8 + e;
  const int g    = q*H_ + h;
  float v = (k < E_) ? W_ih[g*E_ + k] : W_hh[g*H_ + (k - E_)];
  Wf[idx] = f2bf(v);
  if (idx < 4*H_){
    int hh = idx >> 2, qq = idx & 3, gg = qq*H_ + hh;
    biasc[idx] = b_ih[gg] + b_hh[gg];
  }
}

// ---------------------------------------------------------------------------
// encT[t][b][e] = bf16(tanh(x @ W_enc^T + b_enc)), MFMA 16x16x32 bf16.
// ---------------------------------------------------------------------------
__global__ __launch_bounds__(256) void enc_kernel(
    const float* __restrict__ x, const float* __restrict__ W_enc,
    const float* __restrict__ b_enc, unsigned short* __restrict__ encT){
  __shared__ unsigned short As[128*64];
  __shared__ unsigned short Bs[128*64];
  __shared__ float bes[128];
  const int tid = threadIdx.x;
  const int lane = tid & 63, w = tid >> 6;
  const int l15 = lane & 15, lq = lane >> 4;
  const int m0 = blockIdx.x * 128;
  if (tid < 128) bes[tid] = b_enc[tid];

  f32x4 acc[16];
  #pragma unroll
  for (int i=0;i<16;i++) acc[i] = (f32x4)0.f;

  for (int kc = 0; kc < 4; ++kc){
    const int kb = kc*64;
    __syncthreads();
    #pragma unroll
    for (int i=0;i<4;i++){
      int u = i*256 + tid; int r = u>>3, sx = u&7;
      const float* sp = x + (size_t)(m0+r)*D_ + kb + sx*8;
      f32x4 v0 = ntload4f(sp);
      f32x4 v1 = ntload4f(sp+4);
      short8 pk;
      pk[0]=(short)f2bf(v0[0]); pk[1]=(short)f2bf(v0[1]); pk[2]=(short)f2bf(v0[2]); pk[3]=(short)f2bf(v0[3]);
      pk[4]=(short)f2bf(v1[0]); pk[5]=(short)f2bf(v1[1]); pk[6]=(short)f2bf(v1[2]); pk[7]=(short)f2bf(v1[3]);
      int off = (r*128 + sx*16) ^ ((r&7)<<4);
      *(short8*)((char*)As + off) = pk;
    }
    #pragma unroll
    for (int i=0;i<4;i++){
      int u = i*256 + tid; int r = u>>3, sx = u&7;
      const float* sp = W_enc + (size_t)r*D_ + kb + sx*8;
      f32x4 v0 = *(const f32x4*)sp;
      f32x4 v1 = *(const f32x4*)(sp+4);
      short8 pk;
      pk[0]=(short)f2bf(v0[0]); pk[1]=(short)f2bf(v0[1]); pk[2]=(short)f2bf(v0[2]); pk[3]=(short)f2bf(v0[3]);
      pk[4]=(short)f2bf(v1[0]); pk[5]=(short)f2bf(v1[1]); pk[6]=(short)f2bf(v1[2]); pk[7]=(short)f2bf(v1[3]);
      int off = (r*128 + sx*16) ^ ((r&7)<<4);
      *(short8*)((char*)Bs + off) = pk;
    }
    __syncthreads();
    #pragma unroll
    for (int kk=0;kk<2;kk++){
      short8 af[2];
      #pragma unroll
      for (int mi=0;mi<2;mi++){
        int r = 32*w + mi*16 + l15;
        int off = (r*128 + kk*64 + lq*16) ^ ((r&7)<<4);
        af[mi] = *(const short8*)((const char*)As + off);
      }
      #pragma unroll
      for (int nf=0;nf<8;nf++){
        int r = nf*16 + l15;
        int off = (r*128 + kk*64 + lq*16) ^ ((r&7)<<4);
        short8 bfr = *(const short8*)((const char*)Bs + off);
        #pragma unroll
        for (int mi=0;mi<2;mi++)
          acc[mi*8+nf] = __builtin_amdgcn_mfma_f32_16x16x32_bf16(af[mi], bfr, acc[mi*8+nf], 0,0,0);
      }
    }
  }
  #pragma unroll
  for (int mi=0;mi<2;mi++){
    #pragma unroll
    for (int nf=0;nf<8;nf++){
      int col = nf*16 + l15;
      float be = bes[col];
      #pragma unroll
      for (int j=0;j<4;j++){
        int bt = m0 + 32*w + mi*16 + lq*4 + j;
        int b = bt >> 6, tt = bt & 63;
        encT[((size_t)tt*B_ + b)*E_ + col] = f2bf(tanh_(acc[mi*8+nf][j] + be));
      }
    }
  }
}

// ---------------------------------------------------------------------------
// Persistent LSTM recurrence + fused loss reductions.
// 128 blocks x 1024 threads (16 waves, 4/SIMD). Block owns 32 batch rows for
// all 64 steps. Wave w owns h-slice [w*16,w*16+16) x 4 gates, M=32 (2 m-tiles)
// -> each weight fragment feeds 2 MFMAs (2x reuse vs R4). Weights streamed
// 3-deep; enc tile staged into swizzled LDS each step; h in LDS dbuf; c +
// loss accumulators in regs; ONE barrier per step.
// ---------------------------------------------------------------------------
__global__ __launch_bounds__(1024, 4) void rec_kernel(
    const unsigned short* __restrict__ encT,
    const unsigned short* __restrict__ Wf,
    const float* __restrict__ biasc,
    const float* __restrict__ x,
    float* __restrict__ out_hn,
    float* __restrict__ out_loss,
    float* __restrict__ out_ldim,
    float* __restrict__ out_ldt){
  __shared__ char smem[49152];
  char* hb0 = smem;               // hbuf[0]: 32 rows x 512 B (swizzled)
  char* hb1 = smem + 16384;       // hbuf[1]
  char* eb0 = smem + 32768;       // ebuf[0]: 32 rows x 256 B (swizzled)
  char* eb1 = smem + 40960;       // ebuf[1]

  const int tid = threadIdx.x, lane = tid & 63, w = tid >> 6;
  const int l15 = lane & 15, lq = lane >> 4;
  const int b0 = blockIdx.x * 32;
  const int hw = w*16 + l15;

  const f32x4 bias = *(const f32x4*)(biasc + hw*4);
  const unsigned short* wfb = Wf + (size_t)w*24576 + lane*8;  // + (kk*4+q)*512

  // LDS A-frag read bases (row = m*16 + l15)
  const int esw = (l15 & 7) << 4;
  const int ea0 = l15*256 + lq*16;          // m=0
  const int ea1 = (16+l15)*256 + lq*16;     // m=1
  const int ha0 = l15*512 + lq*16;
  const int ha1 = (16+l15)*512 + lq*16;

  // stage mapping (tid<512): row=tid>>4, c=tid&15
  const int srow = tid >> 4, sc = tid & 15;
  const int sdst = (srow*256 + sc*16) ^ ((srow&7)<<4);
  const unsigned short* ssrc = encT + (size_t)(b0 + srow)*E_ + sc*8;  // + t*B_*E_

  // write-pass mapping: wave w -> rows w, w+16; lane -> h chunk lane*4
  const int r1 = w + 16;
  const int wp0 = (w*512 + lane*8) ^ ((w&7)<<4);
  const int wp1 = (r1*512 + lane*8) ^ ((r1&7)<<4);
  const float* xr0 = x + (size_t)(b0+w)*T_*D_ + lane*4;
  const float* xr1 = x + (size_t)(b0+r1)*T_*D_ + lane*4;
  float* lt0 = out_ldt + (size_t)(b0+w)*T_*H_ + lane*4;
  float* lt1 = out_ldt + (size_t)(b0+r1)*T_*H_ + lane*4;

  float c[8];
  #pragma unroll
  for (int i=0;i<8;i++) c[i] = 0.f;
  f32x4 ld0 = (f32x4)0.f, ld1 = (f32x4)0.f;
  float la0 = 0.f, la1 = 0.f;

  // prologue: zero hbuf[0], stage enc t=0
  *(short8*)(hb0 + tid*16) = (short8)(short)0;
  if (tid < 512){
    short8 sv = ntload8(ssrc);
    *(short8*)(eb0 + sdst) = sv;
  }
  __syncthreads();

  for (int t=0; t<T_; ++t){
    char* hrb = (t & 1) ? hb1 : hb0;
    char* hwb = (t & 1) ? hb0 : hb1;
    char* erb = (t & 1) ? eb1 : eb0;
    char* ewb = (t & 1) ? eb0 : eb1;

    // issue next-step enc stage loads + x prefetch (hide under MFMA)
    short8 sv;
    f32x4 xw0, xw1;
    if (t < T_-1){
      if (tid < 512) sv = ntload8(ssrc + (size_t)(t+1)*B_*E_);
      xw0 = ntload4f(xr0 + (size_t)(t+1)*D_);
      xw1 = ntload4f(xr1 + (size_t)(t+1)*D_);
    }

    // weight pipeline prologue (3-deep)
    short8 sb0[4], sb1[4], sb2[4];
    #pragma unroll
    for (int q=0;q<4;q++){
      sb0[q] = *(const short8*)(wfb + (0*4+q)*512);
      sb1[q] = *(const short8*)(wfb + (1*4+q)*512);
      sb2[q] = *(const short8*)(wfb + (2*4+q)*512);
    }

    f32x4 acc[2][4];
    #pragma unroll
    for (int m=0;m<2;m++)
      #pragma unroll
      for (int q=0;q<4;q++) acc[m][q] = (f32x4)0.f;

    #pragma unroll
    for (int kk=0;kk<12;kk++){
      short8 a0, a1;
      if (kk < 4){
        a0 = *(const short8*)(erb + ((ea0 + kk*64) ^ esw));
        a1 = *(const short8*)(erb + ((ea1 + kk*64) ^ esw));
      } else {
        a0 = *(const short8*)(hrb + ((ha0 + (kk-4)*64) ^ esw));
        a1 = *(const short8*)(hrb + ((ha1 + (kk-4)*64) ^ esw));
      }
      short8* cur = (kk%3==0) ? sb0 : ((kk%3==1) ? sb1 : sb2);
      #pragma unroll
      for (int q=0;q<4;q++){
        acc[0][q] = __builtin_amdgcn_mfma_f32_16x16x32_bf16(a0, cur[q], acc[0][q], 0,0,0);
        acc[1][q] = __builtin_amdgcn_mfma_f32_16x16x32_bf16(a1, cur[q], acc[1][q], 0,0,0);
      }
      if (kk+3 < 12){
        #pragma unroll
        for (int q=0;q<4;q++)
          cur[q] = *(const short8*)(wfb + ((kk+3)*4+q)*512);
      }
    }

    // pointwise: lane owns h=hw, rows m*16 + lq*4 + j
    #pragma unroll
    for (int m=0;m<2;m++){
      #pragma unroll
      for (int j=0;j<4;j++){
        float gi = sigm_(acc[m][0][j] + bias[0]);
        float gf = sigm_(acc[m][1][j] + bias[1]);
        float gg = tanh_(acc[m][2][j] + bias[2]);
        float go = sigm_(acc[m][3][j] + bias[3]);
        float cn = gf*c[m*4+j] + gi*gg;
        c[m*4+j] = cn;
        float hn = go * tanh_(cn);
        const int row = m*16 + lq*4 + j;
        *(unsigned short*)(hwb + ((row*512 + hw*2) ^ ((row&7)<<4))) = f2bf(hn);
        if (t == T_-1)
          __builtin_nontemporal_store(hn, out_hn + (size_t)(b0+row)*H_ + hw);
      }
    }
    // stage store for next-step enc (disjoint buffer from erb)
    if (t < T_-1 && tid < 512) *(short8*)(ewb + sdst) = sv;
    __syncthreads();

    // write-pass: full-line ldt stores + fused reductions
    if (t < T_-1){
      u32x2 hv0 = *(const u32x2*)(hwb + wp0);
      u32x2 hv1 = *(const u32x2*)(hwb + wp1);
      f32x4 d0, d1;
      d0[0] = fabsf(__uint_as_float((hv0[0] & 0xFFFFu) << 16) - xw0[0]);
      d0[1] = fabsf(__uint_as_float(hv0[0] & 0xFFFF0000u)     - xw0[1]);
      d0[2] = fabsf(__uint_as_float((hv0[1] & 0xFFFFu) << 16) - xw0[2]);
      d0[3] = fabsf(__uint_as_float(hv0[1] & 0xFFFF0000u)     - xw0[3]);
      d1[0] = fabsf(__uint_as_float((hv1[0] & 0xFFFFu) << 16) - xw1[0]);
      d1[1] = fabsf(__uint_as_float(hv1[0] & 0xFFFF0000u)     - xw1[1]);
      d1[2] = fabsf(__uint_as_float((hv1[1] & 0xFFFFu) << 16) - xw1[2]);
      d1[3] = fabsf(__uint_as_float(hv1[1] & 0xFFFF0000u)     - xw1[3]);
      __builtin_nontemporal_store(d0, (f32x4*)(lt0 + (size_t)t*H_));
      __builtin_nontemporal_store(d1, (f32x4*)(lt1 + (size_t)t*H_));
      ld0 += d0; ld1 += d1;
      float s0 = d0[0]*d0[0] + d0[1]*d0[1] + d0[2]*d0[2] + d0[3]*d0[3];
      float s1 = d1[0]*d1[0] + d1[1]*d1[1] + d1[2]*d1[2] + d1[3]*d1[3];
      #pragma unroll
      for (int off=32; off; off>>=1){ s0 += __shfl_xor(s0, off); s1 += __shfl_xor(s1, off); }
      la0 += sqrtf(s0); la1 += sqrtf(s1);
    } else {
      __builtin_nontemporal_store((f32x4)0.f, (f32x4*)(lt0 + (size_t)t*H_));
      __builtin_nontemporal_store((f32x4)0.f, (f32x4*)(lt1 + (size_t)t*H_));
    }
  }

  // epilogue: loss_dim and loss for rows b0+w, b0+w+16
  const float inv = 1.f/(float)(T_-1);
  *(f32x4*)(out_ldim + (size_t)(b0+w)*H_  + lane*4) = ld0*inv;
  *(f32x4*)(out_ldim + (size_t)(b0+r1)*H_ + lane*4) = ld1*inv;
  if (lane == 0){
    out_loss[b0+w]  = la0*inv;
    out_loss[b0+r1] = la1*inv;
  }
}

// ---------------------------------------------------------------------------
extern "C" void kernel_launch(void* const* d_in, const int* in_sizes, int n_in,
                              void* d_out, int out_size, void* d_ws, size_t ws_size,
                              hipStream_t stream){
  const float* x     = (const float*)d_in[0];
  const float* W_enc = (const float*)d_in[1];
  const float* b_enc = (const float*)d_in[2];
  const float* W_ih  = (const float*)d_in[3];
  const float* b_ih  = (const float*)d_in[4];
  const float* W_hh  = (const float*)d_in[5];
  const float* b_hh  = (const float*)d_in[6];

  // workspace: encT 64 MB | Wf 768 KB | biasc 4 KB
  char* ws = (char*)d_ws;
  unsigned short* encT  = (unsigned short*)(ws);                 // 67,108,864
  unsigned short* Wf    = (unsigned short*)(ws + 67108864);      //    786,432
  float*          biasc = (float*)        (ws + 67895296);       //      4,096

  float* out_hn   = (float*)d_out;
  float* out_loss = out_hn  + (size_t)B_*H_;
  float* out_ldim = out_loss + B_;
  float* out_ldt  = out_ldim + (size_t)B_*H_;

  init_kernel<<<1536, 256, 0, stream>>>(W_ih, b_ih, W_hh, b_hh, Wf, biasc);
  enc_kernel<<<2048, 256, 0, stream>>>(x, W_enc, b_enc, encT);
  rec_kernel<<<128, 1024, 0, stream>>>(encT, Wf, biasc, x, out_hn,
                                       out_loss, out_ldim, out_ldt);
}

// Round 9
// 1491.150 us; speedup vs baseline: 3.1661x; 1.2673x over previous
//
#include <hip/hip_runtime.h>

// Problem constants
#define B_  4096
#define T_  64
#define D_  256
#define E_  128
#define H_  256

typedef __attribute__((ext_vector_type(8))) short short8;
typedef __attribute__((ext_vector_type(4))) float f32x4;
typedef __attribute__((ext_vector_type(2))) unsigned int u32x2;

__device__ inline unsigned short f2bf(float f){
  unsigned u = __float_as_uint(f);
  u += 0x7FFFu + ((u >> 16) & 1u);   // RNE
  return (unsigned short)(u >> 16);
}
__device__ inline float sigm_(float x){ return __fdividef(1.f, 1.f + __expf(-x)); }
__device__ inline float tanh_(float x){
  float e = __expf(2.f * fminf(fmaxf(x, -15.f), 15.f));
  return __fdividef(e - 1.f, e + 1.f);
}
__device__ inline short8 ntload8(const unsigned short* p){
  return __builtin_nontemporal_load((const short8*)p);
}
__device__ inline f32x4 ntload4f(const float* p){
  return __builtin_nontemporal_load((const f32x4*)p);
}
// async global->LDS, 16 B per lane (dest must be wave-uniform base + lane*16)
__device__ inline void gload_lds16(const void* g, void* l){
  __builtin_amdgcn_global_load_lds(
      (const __attribute__((address_space(1))) unsigned int*)g,
      (__attribute__((address_space(3))) unsigned int*)l, 16, 0, 0);
}

// ---------------------------------------------------------------------------
// init: pack weights in LDS staging order: byte(kk,w,q,lane,e) =
//   kk*65536 + w*4096 + q*1024 + lane*16 + e*2   (kk 0..11, w 0..15, q 0..3)
//   value = W'[(w*16 + (lane&15))*4 ... ] :
//     h = w*16 + (lane&15); k = kk*32 + (lane>>4)*8 + e; g = q*256 + h
//     W' = k<128 ? W_ih[g][k] : W_hh[g][k-128]
// biasc[h*4+q] = b_ih[q*256+h] + b_hh[q*256+h].  grid 1536 x 256.
// ---------------------------------------------------------------------------
__global__ __launch_bounds__(256) void init_kernel(
    const float* __restrict__ W_ih, const float* __restrict__ b_ih,
    const float* __restrict__ W_hh, const float* __restrict__ b_hh,
    unsigned short* __restrict__ Wf, float* __restrict__ biasc){
  const int idx  = blockIdx.x*256 + threadIdx.x;
  const int e    = idx & 7;
  const int lane = (idx >> 3) & 63;
  const int q    = (idx >> 9) & 3;
  const int w    = (idx >> 11) & 15;
  const int kk   = idx >> 15;
  const int h    = w*16 + (lane & 15);
  const int k    = kk*32 + (lane >> 4)*8 + e;
  const int g    = q*H_ + h;
  float v = (k < E_) ? W_ih[g*E_ + k] : W_hh[g*H_ + (k - E_)];
  Wf[idx] = f2bf(v);
  if (idx < 4*H_){
    int hh = idx >> 2, qq = idx & 3, gg = qq*H_ + hh;
    biasc[idx] = b_ih[gg] + b_hh[gg];
  }
}

// ---------------------------------------------------------------------------
// encT[t][b][e] = bf16(tanh(x @ W_enc^T + b_enc)), MFMA 16x16x32 bf16.
// ---------------------------------------------------------------------------
__global__ __launch_bounds__(256) void enc_kernel(
    const float* __restrict__ x, const float* __restrict__ W_enc,
    const float* __restrict__ b_enc, unsigned short* __restrict__ encT){
  __shared__ unsigned short As[128*64];
  __shared__ unsigned short Bs[128*64];
  __shared__ float bes[128];
  const int tid = threadIdx.x;
  const int lane = tid & 63, w = tid >> 6;
  const int l15 = lane & 15, lq = lane >> 4;
  const int m0 = blockIdx.x * 128;
  if (tid < 128) bes[tid] = b_enc[tid];

  f32x4 acc[16];
  #pragma unroll
  for (int i=0;i<16;i++) acc[i] = (f32x4)0.f;

  for (int kc = 0; kc < 4; ++kc){
    const int kb = kc*64;
    __syncthreads();
    #pragma unroll
    for (int i=0;i<4;i++){
      int u = i*256 + tid; int r = u>>3, sx = u&7;
      const float* sp = x + (size_t)(m0+r)*D_ + kb + sx*8;
      f32x4 v0 = ntload4f(sp);
      f32x4 v1 = ntload4f(sp+4);
      short8 pk;
      pk[0]=(short)f2bf(v0[0]); pk[1]=(short)f2bf(v0[1]); pk[2]=(short)f2bf(v0[2]); pk[3]=(short)f2bf(v0[3]);
      pk[4]=(short)f2bf(v1[0]); pk[5]=(short)f2bf(v1[1]); pk[6]=(short)f2bf(v1[2]); pk[7]=(short)f2bf(v1[3]);
      int off = (r*128 + sx*16) ^ ((r&7)<<4);
      *(short8*)((char*)As + off) = pk;
    }
    #pragma unroll
    for (int i=0;i<4;i++){
      int u = i*256 + tid; int r = u>>3, sx = u&7;
      const float* sp = W_enc + (size_t)r*D_ + kb + sx*8;
      f32x4 v0 = *(const f32x4*)sp;
      f32x4 v1 = *(const f32x4*)(sp+4);
      short8 pk;
      pk[0]=(short)f2bf(v0[0]); pk[1]=(short)f2bf(v0[1]); pk[2]=(short)f2bf(v0[2]); pk[3]=(short)f2bf(v0[3]);
      pk[4]=(short)f2bf(v1[0]); pk[5]=(short)f2bf(v1[1]); pk[6]=(short)f2bf(v1[2]); pk[7]=(short)f2bf(v1[3]);
      int off = (r*128 + sx*16) ^ ((r&7)<<4);
      *(short8*)((char*)Bs + off) = pk;
    }
    __syncthreads();
    #pragma unroll
    for (int kk=0;kk<2;kk++){
      short8 af[2];
      #pragma unroll
      for (int mi=0;mi<2;mi++){
        int r = 32*w + mi*16 + l15;
        int off = (r*128 + kk*64 + lq*16) ^ ((r&7)<<4);
        af[mi] = *(const short8*)((const char*)As + off);
      }
      #pragma unroll
      for (int nf=0;nf<8;nf++){
        int r = nf*16 + l15;
        int off = (r*128 + kk*64 + lq*16) ^ ((r&7)<<4);
        short8 bfr = *(const short8*)((const char*)Bs + off);
        #pragma unroll
        for (int mi=0;mi<2;mi++)
          acc[mi*8+nf] = __builtin_amdgcn_mfma_f32_16x16x32_bf16(af[mi], bfr, acc[mi*8+nf], 0,0,0);
      }
    }
  }
  #pragma unroll
  for (int mi=0;mi<2;mi++){
    #pragma unroll
    for (int nf=0;nf<8;nf++){
      int col = nf*16 + l15;
      float be = bes[col];
      #pragma unroll
      for (int j=0;j<4;j++){
        int bt = m0 + 32*w + mi*16 + lq*4 + j;
        int b = bt >> 6, tt = bt & 63;
        encT[((size_t)tt*B_ + b)*E_ + col] = f2bf(tanh_(acc[mi*8+nf][j] + be));
      }
    }
  }
}

// ---------------------------------------------------------------------------
// Persistent LSTM recurrence, async-LDS-staged weights.
// 256 blocks x 1024 threads (16 waves, 1 block/CU, 144 KB LDS).
// Block owns 16 batch rows all 64 steps; wave w owns h [w*16,w*16+16) x 4
// gates. Per kk (K-chunk of 32): 64 KB weight chunk is consumed from LDS
// buf p while chunk kk+1 streams into buf p^1 via global_load_lds (no VGPR
// round-trip -> deep queue -> L2-BW-bound, not latency-bound).
// ---------------------------------------------------------------------------
__global__ __launch_bounds__(1024) void rec_kernel(
    const unsigned short* __restrict__ encT,
    const unsigned short* __restrict__ Wf,
    const float* __restrict__ biasc,
    const float* __restrict__ x,
    float* __restrict__ out_hn,
    float* __restrict__ out_loss,
    float* __restrict__ out_ldim,
    float* __restrict__ out_ldt){
  extern __shared__ char smem[];       // 147456 B
  char* wch0 = smem;                   // weight chunk buf 0 (64 KB)
  char* wch1 = smem + 65536;           // weight chunk buf 1 (64 KB)
  char* hb0  = smem + 131072;          // h dbuf 0 (8 KB, swizzled)
  char* hb1  = smem + 139264;          // h dbuf 1 (8 KB)

  const int tid = threadIdx.x, lane = tid & 63, w = tid >> 6;
  const int l15 = lane & 15, lq = lane >> 4;
  const int b0 = blockIdx.x * 16;
  const int hw = w*16 + l15;

  const f32x4 bias = *(const f32x4*)(biasc + hw*4);

  const char* wsrc = (const char*)Wf + tid*16;     // + kk*65536 + r*16384
  const int   sdst = tid*16;                       // + r*16384
  const int   wrb  = w*4096 + lane*16;             // + q*1024 (chunk-relative)

  const unsigned short* ep = encT + (size_t)(b0 + l15)*E_ + lq*8;
  const int rdb = l15*512 + lq*16;
  const int rsw = (l15 & 7) << 4;

  // write-pass mapping: wave w <-> batch row b0+w; lane <-> h[lane*4..+4)
  const int wp0 = (w*512 + lane*8) ^ ((w&7)<<4);
  const float* xr0 = x + (size_t)(b0+w)*T_*D_ + lane*4;
  float* lt0 = out_ldt + (size_t)(b0+w)*T_*H_ + lane*4;

  float c[4] = {0.f,0.f,0.f,0.f};
  f32x4 ld0 = (f32x4)0.f;
  float la0 = 0.f;

  // prologue: zero hbuf0, stage chunk 0 into wch0
  if (tid < 512) *(short8*)(hb0 + tid*16) = (short8)(short)0;
  #pragma unroll
  for (int r=0;r<4;r++)
    gload_lds16(wsrc + r*16384, wch0 + sdst + r*16384);
  __syncthreads();

  int p = 0;
  for (int t=0; t<T_; ++t){
    char* rb = (t & 1) ? hb1 : hb0;
    char* wb = (t & 1) ? hb0 : hb1;

    // per-step A-frags (enc) + x prefetch for write-pass
    short8 ae[4];
    #pragma unroll
    for (int kk=0;kk<4;kk++) ae[kk] = ntload8(ep + (size_t)t*B_*E_ + kk*32);
    f32x4 xw0 = (f32x4)0.f;
    if (t < T_-1) xw0 = ntload4f(xr0 + (size_t)(t+1)*D_);

    f32x4 acc[4];
    #pragma unroll
    for (int q=0;q<4;q++) acc[q] = (f32x4)0.f;

    #pragma unroll
    for (int kk=0;kk<12;kk++){
      // issue staging of next chunk into the other buffer
      const int nk = (kk+1 < 12) ? kk+1 : 0;
      char* sbuf = p ? wch0 : wch1;
      #pragma unroll
      for (int r=0;r<4;r++)
        gload_lds16(wsrc + nk*65536 + r*16384, sbuf + sdst + r*16384);

      // consume chunk kk from current buffer
      const char* cbuf = p ? wch1 : wch0;
      short8 a;
      if (kk < 4) a = ae[kk];
      else        a = *(const short8*)(rb + ((rdb + (kk-4)*64) ^ rsw));
      #pragma unroll
      for (int q=0;q<4;q++){
        short8 bq = *(const short8*)(cbuf + wrb + q*1024);
        acc[q] = __builtin_amdgcn_mfma_f32_16x16x32_bf16(a, bq, acc[q], 0,0,0);
      }
      __syncthreads();   // drains staging (vmcnt) + LDS reads; next buf ready
      p ^= 1;
    }

    // pointwise: lane owns h=hw, rows lq*4+j
    #pragma unroll
    for (int j=0;j<4;j++){
      float gi = sigm_(acc[0][j] + bias[0]);
      float gf = sigm_(acc[1][j] + bias[1]);
      float gg = tanh_(acc[2][j] + bias[2]);
      float go = sigm_(acc[3][j] + bias[3]);
      float cn = gf*c[j] + gi*gg;
      c[j] = cn;
      float hn = go * tanh_(cn);
      const int row = lq*4 + j;
      *(unsigned short*)(wb + ((row*512 + hw*2) ^ ((row&7)<<4))) = f2bf(hn);
      if (t == T_-1)
        __builtin_nontemporal_store(hn, out_hn + (size_t)(b0+row)*H_ + hw);
    }
    __syncthreads();

    // write-pass: full-line coalesced ldt stores + fused reductions
    if (t < T_-1){
      u32x2 hv0 = *(const u32x2*)(wb + wp0);
      f32x4 d0;
      d0[0] = fabsf(__uint_as_float((hv0[0] & 0xFFFFu) << 16) - xw0[0]);
      d0[1] = fabsf(__uint_as_float(hv0[0] & 0xFFFF0000u)     - xw0[1]);
      d0[2] = fabsf(__uint_as_float((hv0[1] & 0xFFFFu) << 16) - xw0[2]);
      d0[3] = fabsf(__uint_as_float(hv0[1] & 0xFFFF0000u)     - xw0[3]);
      __builtin_nontemporal_store(d0, (f32x4*)(lt0 + (size_t)t*H_));
      ld0 += d0;
      float s0 = d0[0]*d0[0] + d0[1]*d0[1] + d0[2]*d0[2] + d0[3]*d0[3];
      #pragma unroll
      for (int off=32; off; off>>=1) s0 += __shfl_xor(s0, off);
      la0 += sqrtf(s0);
    } else {
      __builtin_nontemporal_store((f32x4)0.f, (f32x4*)(lt0 + (size_t)t*H_));
    }
  }

  // epilogue: loss_dim and loss for row b0+w
  const float inv = 1.f/(float)(T_-1);
  *(f32x4*)(out_ldim + (size_t)(b0+w)*H_ + lane*4) = ld0*inv;
  if (lane == 0) out_loss[b0+w] = la0*inv;
}

// ---------------------------------------------------------------------------
extern "C" void kernel_launch(void* const* d_in, const int* in_sizes, int n_in,
                              void* d_out, int out_size, void* d_ws, size_t ws_size,
                              hipStream_t stream){
  const float* x     = (const float*)d_in[0];
  const float* W_enc = (const float*)d_in[1];
  const float* b_enc = (const float*)d_in[2];
  const float* W_ih  = (const float*)d_in[3];
  const float* b_ih  = (const float*)d_in[4];
  const float* W_hh  = (const float*)d_in[5];
  const float* b_hh  = (const float*)d_in[6];

  // workspace: encT 64 MB | Wf 768 KB | biasc 4 KB
  char* ws = (char*)d_ws;
  unsigned short* encT  = (unsigned short*)(ws);                 // 67,108,864
  unsigned short* Wf    = (unsigned short*)(ws + 67108864);      //    786,432
  float*          biasc = (float*)        (ws + 67895296);       //      4,096

  float* out_hn   = (float*)d_out;
  float* out_loss = out_hn  + (size_t)B_*H_;
  float* out_ldim = out_loss + B_;
  float* out_ldt  = out_ldim + (size_t)B_*H_;

  (void)hipFuncSetAttribute((const void*)rec_kernel,
      hipFuncAttributeMaxDynamicSharedMemorySize, 147456);

  init_kernel<<<1536, 256, 0, stream>>>(W_ih, b_ih, W_hh, b_hh, Wf, biasc);
  enc_kernel<<<2048, 256, 0, stream>>>(x, W_enc, b_enc, encT);
  rec_kernel<<<256, 1024, 147456, stream>>>(encT, Wf, biasc, x, out_hn,
                                            out_loss, out_ldim, out_ldt);
}

// Round 11
// 1282.953 us; speedup vs baseline: 3.6799x; 1.1623x over previous
//
#include <hip/hip_runtime.h>

// Problem constants
#define B_  4096
#define T_  64
#define D_  256
#define E_  128
#define H_  256

typedef __attribute__((ext_vector_type(8))) short short8;
typedef __attribute__((ext_vector_type(4))) float f32x4;
typedef __attribute__((ext_vector_type(2))) unsigned int u32x2;

__device__ inline unsigned short f2bf(float f){
  unsigned u = __float_as_uint(f);
  u += 0x7FFFu + ((u >> 16) & 1u);   // RNE
  return (unsigned short)(u >> 16);
}
__device__ inline float sigm_(float x){ return __fdividef(1.f, 1.f + __expf(-x)); }
__device__ inline float tanh_(float x){
  float e = __expf(2.f * fminf(fmaxf(x, -15.f), 15.f));
  return __fdividef(e - 1.f, e + 1.f);
}
__device__ inline short8 ntload8(const unsigned short* p){
  return __builtin_nontemporal_load((const short8*)p);
}
__device__ inline f32x4 ntload4f(const float* p){
  return __builtin_nontemporal_load((const f32x4*)p);
}
// async global->LDS, 16 B per lane (dest wave-uniform base; HW adds lane*16)
__device__ inline void gload_lds16(const void* g, void* l){
  __builtin_amdgcn_global_load_lds(
      (const __attribute__((address_space(1))) unsigned int*)g,
      (__attribute__((address_space(3))) unsigned int*)l, 16, 0, 0);
}

// ---------------------------------------------------------------------------
// init: pack weights in staging order: byte(kk,w,q,lane,e) =
//   kk*65536 + w*4096 + q*1024 + lane*16 + e*2   (kk 0..11, w 0..15, q 0..3)
//     h = w*16 + (lane&15); k = kk*32 + (lane>>4)*8 + e; g = q*256 + h
//     val = k<128 ? W_ih[g][k] : W_hh[g][k-128]
// biasc[h*4+q] = b_ih[q*256+h] + b_hh[q*256+h].  grid 1536 x 256.
// ---------------------------------------------------------------------------
__global__ __launch_bounds__(256) void init_kernel(
    const float* __restrict__ W_ih, const float* __restrict__ b_ih,
    const float* __restrict__ W_hh, const float* __restrict__ b_hh,
    unsigned short* __restrict__ Wf, float* __restrict__ biasc){
  const int idx  = blockIdx.x*256 + threadIdx.x;
  const int e    = idx & 7;
  const int lane = (idx >> 3) & 63;
  const int q    = (idx >> 9) & 3;
  const int w    = (idx >> 11) & 15;
  const int kk   = idx >> 15;
  const int h    = w*16 + (lane & 15);
  const int k    = kk*32 + (lane >> 4)*8 + e;
  const int g    = q*H_ + h;
  float v = (k < E_) ? W_ih[g*E_ + k] : W_hh[g*H_ + (k - E_)];
  Wf[idx] = f2bf(v);
  if (idx < 4*H_){
    int hh = idx >> 2, qq = idx & 3, gg = qq*H_ + hh;
    biasc[idx] = b_ih[gg] + b_hh[gg];
  }
}

// ---------------------------------------------------------------------------
// encT[t][b][e] = bf16(tanh(x @ W_enc^T + b_enc)), MFMA 16x16x32 bf16.
// ---------------------------------------------------------------------------
__global__ __launch_bounds__(256) void enc_kernel(
    const float* __restrict__ x, const float* __restrict__ W_enc,
    const float* __restrict__ b_enc, unsigned short* __restrict__ encT){
  __shared__ unsigned short As[128*64];
  __shared__ unsigned short Bs[128*64];
  __shared__ float bes[128];
  const int tid = threadIdx.x;
  const int lane = tid & 63, w = tid >> 6;
  const int l15 = lane & 15, lq = lane >> 4;
  const int m0 = blockIdx.x * 128;
  if (tid < 128) bes[tid] = b_enc[tid];

  f32x4 acc[16];
  #pragma unroll
  for (int i=0;i<16;i++) acc[i] = (f32x4)0.f;

  for (int kc = 0; kc < 4; ++kc){
    const int kb = kc*64;
    __syncthreads();
    #pragma unroll
    for (int i=0;i<4;i++){
      int u = i*256 + tid; int r = u>>3, sx = u&7;
      const float* sp = x + (size_t)(m0+r)*D_ + kb + sx*8;
      f32x4 v0 = ntload4f(sp);
      f32x4 v1 = ntload4f(sp+4);
      short8 pk;
      pk[0]=(short)f2bf(v0[0]); pk[1]=(short)f2bf(v0[1]); pk[2]=(short)f2bf(v0[2]); pk[3]=(short)f2bf(v0[3]);
      pk[4]=(short)f2bf(v1[0]); pk[5]=(short)f2bf(v1[1]); pk[6]=(short)f2bf(v1[2]); pk[7]=(short)f2bf(v1[3]);
      int off = (r*128 + sx*16) ^ ((r&7)<<4);
      *(short8*)((char*)As + off) = pk;
    }
    #pragma unroll
    for (int i=0;i<4;i++){
      int u = i*256 + tid; int r = u>>3, sx = u&7;
      const float* sp = W_enc + (size_t)r*D_ + kb + sx*8;
      f32x4 v0 = *(const f32x4*)sp;
      f32x4 v1 = *(const f32x4*)(sp+4);
      short8 pk;
      pk[0]=(short)f2bf(v0[0]); pk[1]=(short)f2bf(v0[1]); pk[2]=(short)f2bf(v0[2]); pk[3]=(short)f2bf(v0[3]);
      pk[4]=(short)f2bf(v1[0]); pk[5]=(short)f2bf(v1[1]); pk[6]=(short)f2bf(v1[2]); pk[7]=(short)f2bf(v1[3]);
      int off = (r*128 + sx*16) ^ ((r&7)<<4);
      *(short8*)((char*)Bs + off) = pk;
    }
    __syncthreads();
    #pragma unroll
    for (int kk=0;kk<2;kk++){
      short8 af[2];
      #pragma unroll
      for (int mi=0;mi<2;mi++){
        int r = 32*w + mi*16 + l15;
        int off = (r*128 + kk*64 + lq*16) ^ ((r&7)<<4);
        af[mi] = *(const short8*)((const char*)As + off);
      }
      #pragma unroll
      for (int nf=0;nf<8;nf++){
        int r = nf*16 + l15;
        int off = (r*128 + kk*64 + lq*16) ^ ((r&7)<<4);
        short8 bfr = *(const short8*)((const char*)Bs + off);
        #pragma unroll
        for (int mi=0;mi<2;mi++)
          acc[mi*8+nf] = __builtin_amdgcn_mfma_f32_16x16x32_bf16(af[mi], bfr, acc[mi*8+nf], 0,0,0);
      }
    }
  }
  #pragma unroll
  for (int mi=0;mi<2;mi++){
    #pragma unroll
    for (int nf=0;nf<8;nf++){
      int col = nf*16 + l15;
      float be = bes[col];
      #pragma unroll
      for (int j=0;j<4;j++){
        int bt = m0 + 32*w + mi*16 + lq*4 + j;
        int b = bt >> 6, tt = bt & 63;
        encT[((size_t)tt*B_ + b)*E_ + col] = f2bf(tanh_(acc[mi*8+nf][j] + be));
      }
    }
  }
}

// ---------------------------------------------------------------------------
// Persistent LSTM recurrence, self-paced per-wave weight staging.
// 256 blocks x 1024 threads (16 waves, 1 block/CU, 144 KB LDS).
// Wave w owns gate slice [w*16,w*16+16) x 4 gates; its weight slice of each
// K-chunk (4 KB) streams into a PRIVATE 2-slot LDS ring via global_load_lds,
// paced by counted s_waitcnt vmcnt(4) — no block barrier in the K-loop.
// ONE __syncthreads per step (h double-buffer handoff).
// ---------------------------------------------------------------------------
__global__ __launch_bounds__(1024) void rec_kernel(
    const unsigned short* __restrict__ encT,
    const unsigned short* __restrict__ Wf,
    const float* __restrict__ biasc,
    const float* __restrict__ x,
    float* __restrict__ out_hn,
    float* __restrict__ out_loss,
    float* __restrict__ out_ldim,
    float* __restrict__ out_ldt){
  extern __shared__ char smem[];       // 147456 B
  char* wring = smem;                  // [16 waves][2 slots][4096 B] = 128 KB
  char* hb0   = smem + 131072;         // h dbuf 0 (8 KB, swizzled)
  char* hb1   = smem + 139264;         // h dbuf 1 (8 KB)

  const int tid = threadIdx.x, lane = tid & 63, w = tid >> 6;
  const int l15 = lane & 15, lq = lane >> 4;
  const int b0 = blockIdx.x * 16;
  const int hw = w*16 + l15;

  const f32x4 bias = *(const f32x4*)(biasc + hw*4);

  const char* wsrcw = (const char*)Wf + w*4096 + lane*16;  // + kk*65536 + q*1024
  char* wbase = wring + w*8192;                            // + slot*4096 + q*1024

  const unsigned short* ep = encT + (size_t)(b0 + l15)*E_ + lq*8;
  const int rdb = l15*512 + lq*16;
  const int rsw = (l15 & 7) << 4;

  // write-pass mapping: wave w <-> batch row b0+w; lane <-> h[lane*4..+4)
  const int wp0 = (w*512 + lane*8) ^ ((w&7)<<4);
  const float* xr0 = x + (size_t)(b0+w)*T_*D_ + lane*4;
  float* lt0 = out_ldt + (size_t)(b0+w)*T_*H_ + lane*4;

  float c[4] = {0.f,0.f,0.f,0.f};
  f32x4 ld0 = (f32x4)0.f;
  float la0 = 0.f;

  // prologue: zero hbuf0; stage chunk 0 into slot 0
  if (tid < 512) *(short8*)(hb0 + tid*16) = (short8)(short)0;
  #pragma unroll
  for (int q=0;q<4;q++)
    gload_lds16(wsrcw + q*1024, wbase + q*1024);
  __syncthreads();

  for (int t=0; t<T_; ++t){
    char* rb = (t & 1) ? hb1 : hb0;
    char* wb = (t & 1) ? hb0 : hb1;

    // per-step A-frags (enc) + x prefetch for write-pass
    short8 ae[4];
    #pragma unroll
    for (int kk=0;kk<4;kk++) ae[kk] = ntload8(ep + (size_t)t*B_*E_ + kk*32);
    f32x4 xw0 = (f32x4)0.f;
    if (t < T_-1) xw0 = ntload4f(xr0 + (size_t)(t+1)*D_);

    f32x4 acc[4];
    #pragma unroll
    for (int q=0;q<4;q++) acc[q] = (f32x4)0.f;

    #pragma unroll
    for (int kk=0;kk<12;kk++){
      // issue next chunk (cyclic across steps) into the other slot
      const int nk = (kk+1 < 12) ? kk+1 : 0;
      char* sl = wbase + ((kk+1)&1)*4096;
      #pragma unroll
      for (int q=0;q<4;q++)
        gload_lds16(wsrcw + (size_t)nk*65536 + q*1024, sl + q*1024);
      // wait until chunk kk's 4 loads have landed (4 newer stay in flight)
      asm volatile("s_waitcnt vmcnt(4)" ::: "memory");
      __builtin_amdgcn_sched_barrier(0);
      // consume chunk kk (per-lane 16B of the wave's contiguous 1KB x 4q)
      const char* cl = wbase + (kk&1)*4096 + lane*16;
      short8 a;
      if (kk < 4) a = ae[kk];
      else        a = *(const short8*)(rb + ((rdb + (kk-4)*64) ^ rsw));
      #pragma unroll
      for (int q=0;q<4;q++){
        short8 bq = *(const short8*)(cl + q*1024);
        acc[q] = __builtin_amdgcn_mfma_f32_16x16x32_bf16(a, bq, acc[q], 0,0,0);
      }
    }

    // pointwise: lane owns h=hw, rows lq*4+j
    #pragma unroll
    for (int j=0;j<4;j++){
      float gi = sigm_(acc[0][j] + bias[0]);
      float gf = sigm_(acc[1][j] + bias[1]);
      float gg = tanh_(acc[2][j] + bias[2]);
      float go = sigm_(acc[3][j] + bias[3]);
      float cn = gf*c[j] + gi*gg;
      c[j] = cn;
      float hn = go * tanh_(cn);
      const int row = lq*4 + j;
      *(unsigned short*)(wb + ((row*512 + hw*2) ^ ((row&7)<<4))) = f2bf(hn);
      if (t == T_-1)
        __builtin_nontemporal_store(hn, out_hn + (size_t)(b0+row)*H_ + hw);
    }
    __syncthreads();   // h(t+1) visible; sole block-wide rendezvous per step

    // write-pass: full-line coalesced ldt stores + fused reductions
    if (t < T_-1){
      u32x2 hv0 = *(const u32x2*)(wb + wp0);
      f32x4 d0;
      d0[0] = fabsf(__uint_as_float((hv0[0] & 0xFFFFu) << 16) - xw0[0]);
      d0[1] = fabsf(__uint_as_float(hv0[0] & 0xFFFF0000u)     - xw0[1]);
      d0[2] = fabsf(__uint_as_float((hv0[1] & 0xFFFFu) << 16) - xw0[2]);
      d0[3] = fabsf(__uint_as_float(hv0[1] & 0xFFFF0000u)     - xw0[3]);
      __builtin_nontemporal_store(d0, (f32x4*)(lt0 + (size_t)t*H_));
      ld0 += d0;
      float s0 = d0[0]*d0[0] + d0[1]*d0[1] + d0[2]*d0[2] + d0[3]*d0[3];
      #pragma unroll
      for (int off=32; off; off>>=1) s0 += __shfl_xor(s0, off);
      la0 += sqrtf(s0);
    } else {
      __builtin_nontemporal_store((f32x4)0.f, (f32x4*)(lt0 + (size_t)t*H_));
    }
  }

  // epilogue: loss_dim and loss for row b0+w
  const float inv = 1.f/(float)(T_-1);
  *(f32x4*)(out_ldim + (size_t)(b0+w)*H_ + lane*4) = ld0*inv;
  if (lane == 0) out_loss[b0+w] = la0*inv;
}

// ---------------------------------------------------------------------------
extern "C" void kernel_launch(void* const* d_in, const int* in_sizes, int n_in,
                              void* d_out, int out_size, void* d_ws, size_t ws_size,
                              hipStream_t stream){
  const float* x     = (const float*)d_in[0];
  const float* W_enc = (const float*)d_in[1];
  const float* b_enc = (const float*)d_in[2];
  const float* W_ih  = (const float*)d_in[3];
  const float* b_ih  = (const float*)d_in[4];
  const float* W_hh  = (const float*)d_in[5];
  const float* b_hh  = (const float*)d_in[6];

  // workspace: encT 64 MB | Wf 768 KB | biasc 4 KB
  char* ws = (char*)d_ws;
  unsigned short* encT  = (unsigned short*)(ws);                 // 67,108,864
  unsigned short* Wf    = (unsigned short*)(ws + 67108864);      //    786,432
  float*          biasc = (float*)        (ws + 67895296);       //      4,096

  float* out_hn   = (float*)d_out;
  float* out_loss = out_hn  + (size_t)B_*H_;
  float* out_ldim = out_loss + B_;
  float* out_ldt  = out_ldim + (size_t)B_*H_;

  (void)hipFuncSetAttribute((const void*)rec_kernel,
      hipFuncAttributeMaxDynamicSharedMemorySize, 147456);

  init_kernel<<<1536, 256, 0, stream>>>(W_ih, b_ih, W_hh, b_hh, Wf, biasc);
  enc_kernel<<<2048, 256, 0, stream>>>(x, W_enc, b_enc, encT);
  rec_kernel<<<256, 1024, 147456, stream>>>(encT, Wf, biasc, x, out_hn,
                                            out_loss, out_ldim, out_ldt);
}